// Round 1
// baseline (3497.285 us; speedup 1.0000x reference)
//
#include <hip/hip_runtime.h>

#define D 128
#define K 512
#define HW 4096           // 64*64 pixels per batch image
#define NPIX 262144       // B*H*W = 64*64*64
#define OUT_NORM_ELEMS 33554432  // 64*128*64*64
#define MARGIN 0.005f
#define EPS 1e-12f
#define CHUNK 128         // centroids staged in LDS per iteration

__global__ void zero_kernel(float* __restrict__ p, int n) {
    int i = blockIdx.x * blockDim.x + threadIdx.x;
    if (i < n) p[i] = 0.0f;
}

// One wave per centroid row: normalize and record ||c_norm||^2 (matches ref's
// sum(c_norm*c_norm) which is ~1 but not exactly 1).
__global__ void normalize_centroids(const float* __restrict__ c,
                                    float* __restrict__ cn,
                                    float* __restrict__ nc) {
    int k = blockIdx.x * 4 + (threadIdx.x >> 6);
    int lane = threadIdx.x & 63;
    float2 v = *(const float2*)(c + (size_t)k * D + lane * 2);
    float ss = v.x * v.x + v.y * v.y;
    #pragma unroll
    for (int off = 32; off; off >>= 1) ss += __shfl_xor(ss, off);
    float rinv = 1.0f / fmaxf(sqrtf(ss), EPS);
    float2 o; o.x = v.x * rinv; o.y = v.y * rinv;
    *(float2*)(cn + (size_t)k * D + lane * 2) = o;
    float ss2 = o.x * o.x + o.y * o.y;
    #pragma unroll
    for (int off = 32; off; off >>= 1) ss2 += __shfl_xor(ss2, off);
    if (lane == 0) nc[k] = ss2;
}

// Branchless top-2 (min, second-min) update keeping first index on ties.
#define UPD(dd, cc) do {                                   \
    bool lt1 = (dd) < d1;                                  \
    float nd2 = lt1 ? d1 : (((dd) < d2) ? (dd) : d2);      \
    i1 = lt1 ? (cc) : i1;                                  \
    d1 = lt1 ? (dd) : d1;                                  \
    d2 = nd2;                                              \
} while (0)

__global__ __launch_bounds__(256) void assign_kernel(
    const float* __restrict__ x, const float* __restrict__ cn,
    const float* __restrict__ nc, float* __restrict__ out_norm,
    float* __restrict__ csum, float* __restrict__ ccnt,
    float* __restrict__ oidx)
{
    __shared__ float lds[CHUNK * D];   // 64 KB -> 2 blocks/CU
    const int t = blockIdx.x * 256 + threadIdx.x;   // pixel id
    const int b = t >> 12;             // batch index
    const int p = t & (HW - 1);        // pixel within image
    const float* xp = x + (size_t)b * (D * HW) + p;

    // Load raw row into registers (all indices compile-time static).
    float xr[D];
    #pragma unroll
    for (int d = 0; d < D; ++d) xr[d] = xp[(size_t)d * HW];

    float ss = 0.f;
    #pragma unroll
    for (int d = 0; d < D; ++d) ss += xr[d] * xr[d];
    float norm = sqrtf(ss);
    float rinv = 1.0f / fmaxf(norm, EPS);

    // Write normalized output (same layout as input), keep normalized row.
    float* op = out_norm + (size_t)b * (D * HW) + p;
    #pragma unroll
    for (int d = 0; d < D; ++d) { xr[d] *= rinv; op[(size_t)d * HW] = xr[d]; }

    float d1 = 3.4e38f, d2 = 3.4e38f;
    int i1 = 0;

    for (int cb = 0; cb < K; cb += CHUNK) {
        __syncthreads();
        {   // stage CHUNK centroids into LDS, float4-vectorized
            const float4* src = (const float4*)(cn + (size_t)cb * D);
            float4* dst = (float4*)lds;
            #pragma unroll
            for (int i = 0; i < (CHUNK * D / 4) / 256; ++i)
                dst[i * 256 + threadIdx.x] = src[i * 256 + threadIdx.x];
        }
        __syncthreads();

        for (int c = 0; c < CHUNK; c += 4) {
            const float4* c0 = (const float4*)(lds + (c + 0) * D);
            const float4* c1 = (const float4*)(lds + (c + 1) * D);
            const float4* c2 = (const float4*)(lds + (c + 2) * D);
            const float4* c3 = (const float4*)(lds + (c + 3) * D);
            float a0 = 0.f, a1 = 0.f, a2 = 0.f, a3 = 0.f;
            #pragma unroll
            for (int q = 0; q < D / 4; ++q) {
                float4 v0 = c0[q], v1 = c1[q], v2 = c2[q], v3 = c3[q];
                float x0 = xr[4*q+0], x1 = xr[4*q+1];
                float x2 = xr[4*q+2], x3 = xr[4*q+3];
                a0 += x0 * v0.x; a0 += x1 * v0.y; a0 += x2 * v0.z; a0 += x3 * v0.w;
                a1 += x0 * v1.x; a1 += x1 * v1.y; a1 += x2 * v1.z; a1 += x3 * v1.w;
                a2 += x0 * v2.x; a2 += x1 * v2.y; a2 += x2 * v2.z; a2 += x3 * v2.w;
                a3 += x0 * v3.x; a3 += x1 * v3.y; a3 += x2 * v3.z; a3 += x3 * v3.w;
            }
            float dd0 = nc[cb + c + 0] - 2.f * a0;
            float dd1 = nc[cb + c + 1] - 2.f * a1;
            float dd2 = nc[cb + c + 2] - 2.f * a2;
            float dd3 = nc[cb + c + 3] - 2.f * a3;
            UPD(dd0, cb + c + 0);
            UPD(dd1, cb + c + 1);
            UPD(dd2, cb + c + 2);
            UPD(dd3, cb + c + 3);
        }
    }

    oidx[t] = (float)i1;  // harness reads the whole tuple as f32

    // margin mask: gap = d2 - d1 (row-constant ||x||^2 term cancels)
    if (d2 - d1 > MARGIN) {
        atomicAdd(&ccnt[i1], 1.0f);
        float* cs = csum + (size_t)i1 * D;
        #pragma unroll
        for (int d = 0; d < D; ++d) atomicAdd(&cs[d], xr[d] * norm); // raw = normalized * ||x||
    }
}

extern "C" void kernel_launch(void* const* d_in, const int* in_sizes, int n_in,
                              void* d_out, int out_size, void* d_ws, size_t ws_size,
                              hipStream_t stream) {
    const float* x   = (const float*)d_in[0];
    const float* cen = (const float*)d_in[1];

    float* out      = (float*)d_out;
    float* out_norm = out;                       // 33554432
    float* csum     = out + OUT_NORM_ELEMS;      // 512*128
    float* ccnt     = csum + (size_t)K * D;      // 512
    float* oidx     = ccnt + K;                  // 262144

    float* cn = (float*)d_ws;                    // normalized centroids (K*D)
    float* nc = cn + (size_t)K * D;              // ||c_norm||^2 per centroid (K)

    // cluster sums/counts are accumulated with atomics -> must zero each call
    hipLaunchKernelGGL(zero_kernel, dim3((K * D + K + 255) / 256), dim3(256), 0, stream,
                       csum, K * D + K);
    hipLaunchKernelGGL(normalize_centroids, dim3(K / 4), dim3(256), 0, stream,
                       cen, cn, nc);
    hipLaunchKernelGGL(assign_kernel, dim3(NPIX / 256), dim3(256), 0, stream,
                       x, cn, nc, out_norm, csum, ccnt, oidx);
}

// Round 2
// 1830.370 us; speedup vs baseline: 1.9107x; 1.9107x over previous
//
#include <hip/hip_runtime.h>

#define D 128
#define K 512
#define HW 4096                  // 64*64 pixels per image
#define NPIX 262144              // B*H*W
#define OUT_NORM_ELEMS 33554432  // 64*128*64*64
#define MARGIN 0.005f
#define EPS 1e-12f

__global__ void zero_kernel(float* __restrict__ p, int n) {
    int i = blockIdx.x * blockDim.x + threadIdx.x;
    if (i < n) p[i] = 0.0f;
}

// One wave per centroid row: normalize, store TRANSPOSED cnT[d][c], plus
// ||c_norm||^2 (matches ref's sum(c_norm*c_norm), ~1 but not exactly 1).
__global__ void normalize_centroids(const float* __restrict__ c,
                                    float* __restrict__ cnT,
                                    float* __restrict__ nc) {
    int k = blockIdx.x * 4 + (threadIdx.x >> 6);
    int lane = threadIdx.x & 63;
    float2 v = *(const float2*)(c + (size_t)k * D + lane * 2);
    float ss = v.x * v.x + v.y * v.y;
    #pragma unroll
    for (int off = 32; off; off >>= 1) ss += __shfl_xor(ss, off);
    float rinv = 1.0f / fmaxf(sqrtf(ss), EPS);
    float ox = v.x * rinv, oy = v.y * rinv;
    cnT[(size_t)(2 * lane) * K + k] = ox;
    cnT[(size_t)(2 * lane + 1) * K + k] = oy;
    float ss2 = ox * ox + oy * oy;
    #pragma unroll
    for (int off = 32; off; off >>= 1) ss2 += __shfl_xor(ss2, off);
    if (lane == 0) nc[k] = ss2;
}

// Streaming normalize of x: 4 pixels per thread, two passes over d
// (second pass is L2/L3-warm). Low VGPR -> max occupancy.
__global__ __launch_bounds__(256) void normalize_x(
    const float* __restrict__ x, float* __restrict__ xn,
    float* __restrict__ norms)
{
    int t = blockIdx.x * 256 + threadIdx.x;   // handles pixels 4t..4t+3
    int pg = t * 4;
    int b = pg >> 12;
    int pp = pg & (HW - 1);
    const float* xp = x + (size_t)b * (D * HW) + pp;

    float4 ss = make_float4(0.f, 0.f, 0.f, 0.f);
    #pragma unroll 8
    for (int d = 0; d < D; ++d) {
        float4 v = *(const float4*)(xp + (size_t)d * HW);
        ss.x += v.x * v.x; ss.y += v.y * v.y;
        ss.z += v.z * v.z; ss.w += v.w * v.w;
    }
    float4 nrm = make_float4(sqrtf(ss.x), sqrtf(ss.y), sqrtf(ss.z), sqrtf(ss.w));
    *(float4*)&norms[pg] = nrm;
    float4 ri = make_float4(1.f / fmaxf(nrm.x, EPS), 1.f / fmaxf(nrm.y, EPS),
                            1.f / fmaxf(nrm.z, EPS), 1.f / fmaxf(nrm.w, EPS));
    float* op = xn + (size_t)b * (D * HW) + pp;
    #pragma unroll 8
    for (int d = 0; d < D; ++d) {
        float4 v = *(const float4*)(xp + (size_t)d * HW);
        v.x *= ri.x; v.y *= ri.y; v.z *= ri.z; v.w *= ri.w;
        *(float4*)(op + (size_t)d * HW) = v;
    }
}

// Fused fp32 GEMM (dist) + online top-2 + idx + masked scatter.
// Block: 64 pixels x 512 centroids. Thread tile: 4 pixels x 8 centroids.
__global__ __launch_bounds__(256) void gemm_top2(
    const float* __restrict__ xn, const float* __restrict__ cnT,
    const float* __restrict__ nc, const float* __restrict__ norms,
    float* __restrict__ csum, float* __restrict__ ccnt,
    float* __restrict__ oidx)
{
    __shared__ float As[D * 68];      // [d][p], stride 68 (pad kills conflicts)
    __shared__ float Bs[32 * 128];    // [k][c] chunk
    __shared__ float nc_s[128];
    __shared__ float norm_s[64];
    __shared__ int   idx_s[64];
    __shared__ float gap_s[64];

    const int t = threadIdx.x;
    const int pix0 = blockIdx.x * 64;
    const int b = pix0 >> 12;
    const int p0 = pix0 & (HW - 1);
    const float* xb = xn + (size_t)b * (D * HW) + p0;

    // Stage normalized A tile [d][p] (coalesced global, conflict-free LDS)
    {
        int pp = (t & 15) * 4;
        int d0 = t >> 4;
        #pragma unroll
        for (int r = 0; r < 8; ++r) {
            int d = d0 + 16 * r;
            float4 v = *(const float4*)(xb + (size_t)d * HW + pp);
            *(float4*)(&As[d * 68 + pp]) = v;
        }
        if (t < 64) norm_s[t] = norms[pix0 + t];
    }

    const int j = t & 15;   // centroid sub-group: owns {4j..4j+3, 64+4j..64+4j+3}
    const int g = t >> 4;   // pixel group: pixels 4g..4g+3

    float d1[4], d2[4]; int i1[4];
    #pragma unroll
    for (int p = 0; p < 4; ++p) { d1[p] = 3.4e38f; d2[p] = 3.4e38f; i1[p] = 0; }

    for (int cb = 0; cb < K; cb += 128) {
        __syncthreads();
        if (t < 32) *(float4*)&nc_s[t * 4] = *(const float4*)&nc[cb + t * 4];

        float acc[4][8];
        #pragma unroll
        for (int p = 0; p < 4; ++p)
            #pragma unroll
            for (int c = 0; c < 8; ++c) acc[p][c] = 0.f;

        for (int kk = 0; kk < D; kk += 32) {
            {   // stage Bs[k][c] from transposed centroids (coalesced)
                int c4 = (t & 31) * 4;
                int k0 = t >> 5;
                #pragma unroll
                for (int r = 0; r < 4; ++r) {
                    int k = k0 + 8 * r;
                    *(float4*)&Bs[k * 128 + c4] =
                        *(const float4*)&cnT[(size_t)(kk + k) * K + cb + c4];
                }
            }
            __syncthreads();
            #pragma unroll
            for (int k = 0; k < 32; ++k) {
                float4 av = *(const float4*)&As[(kk + k) * 68 + 4 * g];
                float4 b0 = *(const float4*)&Bs[k * 128 + 4 * j];
                float4 b1 = *(const float4*)&Bs[k * 128 + 64 + 4 * j];
                acc[0][0] += av.x * b0.x; acc[0][1] += av.x * b0.y;
                acc[0][2] += av.x * b0.z; acc[0][3] += av.x * b0.w;
                acc[0][4] += av.x * b1.x; acc[0][5] += av.x * b1.y;
                acc[0][6] += av.x * b1.z; acc[0][7] += av.x * b1.w;
                acc[1][0] += av.y * b0.x; acc[1][1] += av.y * b0.y;
                acc[1][2] += av.y * b0.z; acc[1][3] += av.y * b0.w;
                acc[1][4] += av.y * b1.x; acc[1][5] += av.y * b1.y;
                acc[1][6] += av.y * b1.z; acc[1][7] += av.y * b1.w;
                acc[2][0] += av.z * b0.x; acc[2][1] += av.z * b0.y;
                acc[2][2] += av.z * b0.z; acc[2][3] += av.z * b0.w;
                acc[2][4] += av.z * b1.x; acc[2][5] += av.z * b1.y;
                acc[2][6] += av.z * b1.z; acc[2][7] += av.z * b1.w;
                acc[3][0] += av.w * b0.x; acc[3][1] += av.w * b0.y;
                acc[3][2] += av.w * b0.z; acc[3][3] += av.w * b0.w;
                acc[3][4] += av.w * b1.x; acc[3][5] += av.w * b1.y;
                acc[3][6] += av.w * b1.z; acc[3][7] += av.w * b1.w;
            }
            __syncthreads();
        }

        // online top-2 update (ascending centroid index within thread)
        #pragma unroll
        for (int p = 0; p < 4; ++p) {
            #pragma unroll
            for (int c = 0; c < 8; ++c) {
                int coff = (c < 4) ? (4 * j + c) : (64 + 4 * j + (c - 4));
                float dd = nc_s[coff] - 2.f * acc[p][c];
                int cidx = cb + coff;
                bool lt1 = dd < d1[p];
                float nd2 = lt1 ? d1[p] : ((dd < d2[p]) ? dd : d2[p]);
                i1[p] = lt1 ? cidx : i1[p];
                d1[p] = lt1 ? dd : d1[p];
                d2[p] = nd2;
            }
        }
    }

    // merge top-2 across the 16 lanes sharing the same pixels (tie -> lower idx)
    #pragma unroll
    for (int m = 1; m < 16; m <<= 1) {
        #pragma unroll
        for (int p = 0; p < 4; ++p) {
            float o1 = __shfl_xor(d1[p], m);
            float o2 = __shfl_xor(d2[p], m);
            int   oi = __shfl_xor(i1[p], m);
            bool take = (o1 < d1[p]) || (o1 == d1[p] && oi < i1[p]);
            float loser = take ? d1[p] : o1;
            d2[p] = fminf(loser, fminf(d2[p], o2));
            if (take) { d1[p] = o1; i1[p] = oi; }
        }
    }
    if (j == 0) {
        #pragma unroll
        for (int p = 0; p < 4; ++p) {
            idx_s[4 * g + p] = i1[p];
            gap_s[4 * g + p] = d2[p] - d1[p];
        }
    }
    __syncthreads();

    if (t < 64) oidx[pix0 + t] = (float)idx_s[t];

    // masked scatter of RAW rows (= normalized_in_LDS * norm), 4 threads/pixel
    {
        int p = t & 63;
        int part = t >> 6;
        if (gap_s[p] > MARGIN) {
            int kc = idx_s[p];
            float nrm = norm_s[p];
            float* cs = csum + (size_t)kc * D + part * 32;
            #pragma unroll
            for (int dq = 0; dq < 32; ++dq)
                atomicAdd(&cs[dq], As[(part * 32 + dq) * 68 + p] * nrm);
            if (part == 0) atomicAdd(&ccnt[kc], 1.0f);
        }
    }
}

extern "C" void kernel_launch(void* const* d_in, const int* in_sizes, int n_in,
                              void* d_out, int out_size, void* d_ws, size_t ws_size,
                              hipStream_t stream) {
    const float* x   = (const float*)d_in[0];
    const float* cen = (const float*)d_in[1];

    float* out      = (float*)d_out;
    float* out_norm = out;                       // 33554432
    float* csum     = out + OUT_NORM_ELEMS;      // 512*128
    float* ccnt     = csum + (size_t)K * D;      // 512
    float* oidx     = ccnt + K;                  // 262144

    float* cnT   = (float*)d_ws;                 // [128][512] transposed norm'd centroids
    float* nc    = cnT + (size_t)D * K;          // [512] ||c_norm||^2
    float* norms = nc + K;                       // [262144] per-pixel ||x||

    hipLaunchKernelGGL(zero_kernel, dim3((K * D + K + 255) / 256), dim3(256), 0, stream,
                       csum, K * D + K);
    hipLaunchKernelGGL(normalize_centroids, dim3(K / 4), dim3(256), 0, stream,
                       cen, cnT, nc);
    hipLaunchKernelGGL(normalize_x, dim3(NPIX / 4 / 256), dim3(256), 0, stream,
                       x, out_norm, norms);
    hipLaunchKernelGGL(gemm_top2, dim3(NPIX / 64), dim3(256), 0, stream,
                       out_norm, cnT, nc, norms, csum, ccnt, oidx);
}

// Round 4
// 943.996 us; speedup vs baseline: 3.7048x; 1.9390x over previous
//
#include <hip/hip_runtime.h>
#include <stdint.h>

#define D 128
#define K 512
#define HW 4096
#define NPIX 262144
#define OUT_NORM_ELEMS 33554432
#define MARGIN 0.005f
#define EPS 1e-12f
#define LOSCALE 2048.0f
#define RSCALE (1.0f / 2048.0f)

typedef _Float16 f16x8 __attribute__((ext_vector_type(8)));
typedef float f32x4 __attribute__((ext_vector_type(4)));

// ---- LDS layout (bytes) ----
#define SM_BBUF0   0
#define SM_BBUF1   65536
#define SM_NC      131072      // 512 f32
#define SM_MG1     133120      // 2*128 f32
#define SM_MG2     134144      // 2*128 f32
#define SM_MGI     135168      // 2*128 i32
#define SM_NORM    136192      // 128 f32
#define SM_RINV    136704      // 128 f32
#define SM_IDXSEL  137216      // 128 i32
#define SM_PSUM    137728      // 4*128 f32
#define SM_BYTES   139776
#define XSTRIDE    130         // fp32 x-stage stride

__device__ __forceinline__ short f2h(float f) {
    _Float16 h = (_Float16)f; return *reinterpret_cast<short*>(&h);
}
__device__ __forceinline__ float h2f(short s) {
    _Float16 h = *reinterpret_cast<_Float16*>(&s); return (float)h;
}

#define FENCE() asm volatile("" ::: "memory")

__global__ void zero_kernel(float* __restrict__ p, int n) {
    int i = blockIdx.x * blockDim.x + threadIdx.x;
    if (i < n) p[i] = 0.0f;
}

// One wave per centroid: fp32 normalize; store fp16 hi row + 2048-scaled fp16
// lo row ([k][256] halfs: 0..127 hi, 128..255 lo'); nc = sum(c_norm^2) fp32.
__global__ void normalize_centroids(const float* __restrict__ c,
                                    short* __restrict__ csp,
                                    float* __restrict__ nc) {
    int k = blockIdx.x * 4 + (threadIdx.x >> 6);
    int lane = threadIdx.x & 63;
    float2 v = *(const float2*)(c + (size_t)k * D + lane * 2);
    float ss = v.x * v.x + v.y * v.y;
    #pragma unroll
    for (int off = 32; off; off >>= 1) ss += __shfl_xor(ss, off);
    float rinv = 1.0f / fmaxf(sqrtf(ss), EPS);
    float ox = v.x * rinv, oy = v.y * rinv;
    short hx = f2h(ox), hy = f2h(oy);
    short lx = f2h((ox - h2f(hx)) * LOSCALE);
    short ly = f2h((oy - h2f(hy)) * LOSCALE);
    *(short2*)&csp[(size_t)k * 256 + 2 * lane]       = make_short2(hx, hy);
    *(short2*)&csp[(size_t)k * 256 + 128 + 2 * lane] = make_short2(lx, ly);
    float ss2 = ox * ox + oy * oy;
    #pragma unroll
    for (int off = 32; off; off >>= 1) ss2 += __shfl_xor(ss2, off);
    if (lane == 0) nc[k] = ss2;
}

// Branchless top-2 update (keep first index on ties)
#define UPD(dd, cc, ri) do {                                      \
    bool lt1 = (dd) < d1[ri];                                     \
    float nd2 = lt1 ? d1[ri] : (((dd) < d2[ri]) ? (dd) : d2[ri]); \
    i1[ri] = lt1 ? (cc) : i1[ri];                                 \
    d1[ri] = lt1 ? (dd) : d1[ri];                                 \
    d2[ri] = nd2;                                                 \
} while (0)

__global__ __launch_bounds__(512, 2) void fused_kernel(
    const float* __restrict__ x, const short* __restrict__ csp,
    const float* __restrict__ nc, float* __restrict__ out_norm,
    float* __restrict__ csum, float* __restrict__ ccnt,
    float* __restrict__ oidx)
{
    __shared__ char smem[SM_BYTES] __attribute__((aligned(16)));
    float* lds_f   = (float*)smem;
    float* nc_s    = (float*)(smem + SM_NC);
    float* mg1     = (float*)(smem + SM_MG1);
    float* mg2     = (float*)(smem + SM_MG2);
    int*   mgi     = (int*)(smem + SM_MGI);
    float* norm_s  = (float*)(smem + SM_NORM);
    float* rinv_s  = (float*)(smem + SM_RINV);
    int*   idxsel  = (int*)(smem + SM_IDXSEL);
    float* psum    = (float*)(smem + SM_PSUM);

    const int t    = threadIdx.x;
    const int lane = t & 63;
    const int wid  = t >> 6;
    const int wm   = wid >> 1;       // 0..3  (32-pixel row block)
    const int wn   = wid & 1;        // 0..1  (64-centroid col block per chunk)
    const int lb15 = lane & 15;
    const int kl4  = lane >> 4;      // 0..3
    const int kl   = kl4 * 16;       // byte offset of k-slice within half-row
    const int lswzB = (lb15 & 7) << 4;   // row&7 XOR-swizzle on byte bits 4-6

    const int pix0 = blockIdx.x * 128;
    const int b    = pix0 >> 12;
    const int px0  = pix0 & (HW - 1);
    const float* xg = x + (size_t)b * (D * HW) + px0;

    // ---- prologue: stage raw x tile [d][px] fp32 ----
    #pragma unroll
    for (int r = 0; r < 16; ++r) {
        int gid = r * 512 + t;
        int d = gid >> 6;
        int px2 = (gid & 63) * 2;
        float2 v = *(const float2*)(xg + (size_t)d * HW + px2);
        *(float2*)&lds_f[d * XSTRIDE + px2] = v;
    }
    nc_s[t] = nc[t];
    __syncthreads();

    // ---- norms ----
    {
        int q = t >> 7, px = t & 127;
        float s = 0.f;
        #pragma unroll
        for (int i = 0; i < 32; ++i) {
            float v = lds_f[(q * 32 + i) * XSTRIDE + px];
            s += v * v;
        }
        psum[q * 128 + px] = s;
    }
    __syncthreads();
    if (t < 128) {
        float s = psum[t] + psum[128 + t] + psum[256 + t] + psum[384 + t];
        float nrm = sqrtf(s);
        norm_s[t] = nrm;
        rinv_s[t] = 1.f / fmaxf(nrm, EPS);
    }
    __syncthreads();

    // ---- write normalized output (fp32, original layout) ----
    float* og = out_norm + (size_t)b * (D * HW) + px0;
    #pragma unroll
    for (int r = 0; r < 16; ++r) {
        int gid = r * 512 + t;
        int d = gid >> 6;
        int px2 = (gid & 63) * 2;
        float2 v = *(float2*)&lds_f[d * XSTRIDE + px2];
        float2 rv = *(float2*)&rinv_s[px2];
        v.x *= rv.x; v.y *= rv.y;
        *(float2*)(og + (size_t)d * HW + px2) = v;
    }

    // ---- build A fragments (fp16 hi + 2048-scaled fp16 lo) in registers ----
    f16x8 ahi[2][4], alo[2][4];
    #pragma unroll
    for (int mf = 0; mf < 2; ++mf) {
        int px = wm * 32 + mf * 16 + lb15;
        float rinv = rinv_s[px];
        #pragma unroll
        for (int kq = 0; kq < 4; ++kq) {
            f16x8 h, l;
            #pragma unroll
            for (int e = 0; e < 8; ++e) {
                int d = kq * 32 + kl4 * 8 + e;
                float v = lds_f[d * XSTRIDE + px] * rinv;
                _Float16 hv = (_Float16)v;
                h[e] = hv;
                l[e] = (_Float16)((v - (float)hv) * LOSCALE);
            }
            ahi[mf][kq] = h; alo[mf][kq] = l;
        }
    }
    __syncthreads();      // x region dead -> becomes B buffers

    // ---- B staging (global_load_lds, source pre-swizzled g=row&7) ----
    const char* cspb = (const char*)csp;
    auto stageB = [&](int bufoff, int cb) {
        const char* src = cspb + (size_t)cb * 512;
        #pragma unroll
        for (int r = 0; r < 8; ++r) {
            int P  = wid * 8192 + r * 1024;
            int Pl = P + lane * 16;
            int row = Pl >> 9;
            int goff = Pl ^ ((row & 7) << 4);
            __builtin_amdgcn_global_load_lds(
                (const __attribute__((address_space(1))) uint32_t*)(src + goff),
                (__attribute__((address_space(3))) uint32_t*)(smem + bufoff + P),
                16, 0, 0);
        }
    };

    // ---- top-2 state: 8 pixel-rows per lane (mf*4 + j) ----
    float d1[8], d2[8]; int i1[8];
    #pragma unroll
    for (int r = 0; r < 8; ++r) { d1[r] = 3.4e38f; d2[r] = 3.4e38f; i1[r] = 0; }

    stageB(SM_BBUF0, 0);

    for (int c4 = 0; c4 < 4; ++c4) {
        const int cb = c4 * 128;
        const int bufoff = (c4 & 1) ? SM_BBUF1 : SM_BBUF0;
        if (c4 < 3) stageB((c4 & 1) ? SM_BBUF0 : SM_BBUF1, cb + 128);
        if (c4 < 3) { asm volatile("s_waitcnt vmcnt(8)" ::: "memory"); }
        else        { asm volatile("s_waitcnt vmcnt(0)" ::: "memory"); }
        __builtin_amdgcn_s_barrier();
        FENCE();

        f32x4 am[2][4], ac[2][4];   // main + scaled-cross accumulators
        #pragma unroll
        for (int mf = 0; mf < 2; ++mf)
            #pragma unroll
            for (int nf = 0; nf < 4; ++nf) {
                am[mf][nf] = (f32x4){0.f, 0.f, 0.f, 0.f};
                ac[mf][nf] = (f32x4){0.f, 0.f, 0.f, 0.f};
            }

        #pragma unroll
        for (int kq = 0; kq < 4; ++kq) {
            #pragma unroll
            for (int nf = 0; nf < 4; ++nf) {
                const int rowb = (wn * 64 + nf * 16 + lb15) * 512;
                f16x8 bh = *(const f16x8*)(smem + bufoff + rowb + ((kq * 64 + kl) ^ lswzB));
                f16x8 bl = *(const f16x8*)(smem + bufoff + rowb + ((256 + kq * 64 + kl) ^ lswzB));
                #pragma unroll
                for (int mf = 0; mf < 2; ++mf) {
                    am[mf][nf] = __builtin_amdgcn_mfma_f32_16x16x32_f16(ahi[mf][kq], bh, am[mf][nf], 0, 0, 0);
                    ac[mf][nf] = __builtin_amdgcn_mfma_f32_16x16x32_f16(ahi[mf][kq], bl, ac[mf][nf], 0, 0, 0);
                    ac[mf][nf] = __builtin_amdgcn_mfma_f32_16x16x32_f16(alo[mf][kq], bh, ac[mf][nf], 0, 0, 0);
                }
            }
        }

        // online top-2 from this chunk: dist = nc - 2*main - (2/2048)*cross
        #pragma unroll
        for (int nf = 0; nf < 4; ++nf) {
            int cid = cb + wn * 64 + nf * 16 + lb15;
            float ncv = nc_s[cid];
            #pragma unroll
            for (int mf = 0; mf < 2; ++mf) {
                #pragma unroll
                for (int j = 0; j < 4; ++j) {
                    int ri = mf * 4 + j;
                    float dd = ncv - 2.f * am[mf][nf][j] - (2.f * RSCALE) * ac[mf][nf][j];
                    UPD(dd, cid, ri);
                }
            }
        }

        FENCE();
        __builtin_amdgcn_s_barrier();
        FENCE();
    }

    // ---- butterfly merge across the 16 centroid lanes ----
    #pragma unroll
    for (int r = 0; r < 8; ++r) {
        #pragma unroll
        for (int m = 1; m < 16; m <<= 1) {
            float o1 = __shfl_xor(d1[r], m);
            float o2 = __shfl_xor(d2[r], m);
            int   oi = __shfl_xor(i1[r], m);
            bool take = (o1 < d1[r]) || (o1 == d1[r] && oi < i1[r]);
            float loser = take ? d1[r] : o1;
            d2[r] = fminf(loser, fminf(d2[r], o2));
            if (take) { d1[r] = o1; i1[r] = oi; }
        }
    }
    if (lb15 == 0) {
        #pragma unroll
        for (int mf = 0; mf < 2; ++mf)
            #pragma unroll
            for (int j = 0; j < 4; ++j) {
                int row = wm * 32 + mf * 16 + kl4 * 4 + j;
                mg1[wn * 128 + row] = d1[mf * 4 + j];
                mg2[wn * 128 + row] = d2[mf * 4 + j];
                mgi[wn * 128 + row] = i1[mf * 4 + j];
            }
    }
    __syncthreads();

    // ---- final cross-wave merge, idx/mask outputs ----
    if (t < 128) {
        float bd1 = 3.4e38f, bd2 = 3.4e38f; int bi = 0;
        #pragma unroll
        for (int w = 0; w < 2; ++w) {
            float a1 = mg1[w * 128 + t], a2 = mg2[w * 128 + t];
            int ai = mgi[w * 128 + t];
            if (a1 < bd1 || (a1 == bd1 && ai < bi)) {
                bd2 = fminf(bd1, fminf(a2, bd2));
                bd1 = a1; bi = ai;
            } else {
                bd2 = fminf(bd2, a1);
            }
        }
        oidx[pix0 + t] = (float)bi;
        bool sel = (bd2 - bd1) > MARGIN;
        idxsel[t] = sel ? bi : -1;
        if (sel) atomicAdd(&ccnt[bi], 1.0f);
    }
    __syncthreads();

    // ---- masked scatter of raw rows from register fragments ----
    if (wn == 0) {
        #pragma unroll
        for (int mf = 0; mf < 2; ++mf) {
            int px = wm * 32 + mf * 16 + lb15;
            int isel = idxsel[px];
            if (isel >= 0) {
                float nrm = norm_s[px];
                float* cs = csum + (size_t)isel * D;
                #pragma unroll
                for (int kq = 0; kq < 4; ++kq)
                    #pragma unroll
                    for (int e = 0; e < 8; ++e) {
                        int d = kq * 32 + kl4 * 8 + e;
                        float raw = ((float)ahi[mf][kq][e] +
                                     (float)alo[mf][kq][e] * RSCALE) * nrm;
                        atomicAdd(&cs[d], raw);
                    }
            }
        }
    }
}

extern "C" void kernel_launch(void* const* d_in, const int* in_sizes, int n_in,
                              void* d_out, int out_size, void* d_ws, size_t ws_size,
                              hipStream_t stream) {
    const float* x   = (const float*)d_in[0];
    const float* cen = (const float*)d_in[1];

    float* out      = (float*)d_out;
    float* out_norm = out;                       // 33554432
    float* csum     = out + OUT_NORM_ELEMS;      // 512*128
    float* ccnt     = csum + (size_t)K * D;      // 512
    float* oidx     = ccnt + K;                  // 262144

    short* csp = (short*)d_ws;                   // [512][256] fp16 hi|lo'
    float* nc  = (float*)((char*)d_ws + (size_t)K * 256 * 2);  // [512]

    hipLaunchKernelGGL(zero_kernel, dim3((K * D + K + 255) / 256), dim3(256), 0, stream,
                       csum, K * D + K);
    hipLaunchKernelGGL(normalize_centroids, dim3(K / 4), dim3(256), 0, stream,
                       cen, csp, nc);
    hipLaunchKernelGGL(fused_kernel, dim3(NPIX / 128), dim3(512), 0, stream,
                       x, csp, nc, out_norm, csum, ccnt, oidx);
}

// Round 5
// 415.494 us; speedup vs baseline: 8.4172x; 2.2720x over previous
//
#include <hip/hip_runtime.h>
#include <stdint.h>

#define D 128
#define K 512
#define HW 4096
#define NPIX 262144
#define OUT_NORM_ELEMS 33554432
#define MARGIN 0.005f
#define EPS 1e-12f
#define LOSCALE 2048.0f
#define RSCALE (1.0f / 2048.0f)

typedef _Float16 f16x8 __attribute__((ext_vector_type(8)));
typedef _Float16 f16x2 __attribute__((ext_vector_type(2)));
typedef float f32x4 __attribute__((ext_vector_type(4)));

// ---- LDS layout (bytes), CHUNK=64 centroids ----
#define SM_BBUF0   0
#define SM_BBUF1   32768
#define SM_NC      66560      // 512 f32   (x-stage, 66552 B, overlaps B-bufs only)
#define SM_MG1     68608      // 2*128 f32
#define SM_MG2     69632      // 2*128 f32
#define SM_MGI     70656      // 2*128 i32
#define SM_NORM    71680      // 128 f32
#define SM_RINV    72192      // 128 f32
#define SM_PSUM    72704      // 4*128 f32
#define SM_BYTES   74752
#define XSTRIDE    130        // fp32 x-stage stride

__device__ __forceinline__ short f2h(float f) {
    _Float16 h = (_Float16)f; return *reinterpret_cast<short*>(&h);
}
__device__ __forceinline__ float h2f(short s) {
    _Float16 h = *reinterpret_cast<_Float16*>(&s); return (float)h;
}

#define FENCE() asm volatile("" ::: "memory")

__global__ void zero_kernel(float* __restrict__ p, int n) {
    int i = blockIdx.x * blockDim.x + threadIdx.x;
    if (i < n) p[i] = 0.0f;
}

// One wave per centroid: fp32 normalize; store fp16 hi row + 2048-scaled fp16
// lo row ([k][256] halfs: 0..127 hi, 128..255 lo'); nc = sum(c_norm^2) fp32.
__global__ void normalize_centroids(const float* __restrict__ c,
                                    short* __restrict__ csp,
                                    float* __restrict__ nc) {
    int k = blockIdx.x * 4 + (threadIdx.x >> 6);
    int lane = threadIdx.x & 63;
    float2 v = *(const float2*)(c + (size_t)k * D + lane * 2);
    float ss = v.x * v.x + v.y * v.y;
    #pragma unroll
    for (int off = 32; off; off >>= 1) ss += __shfl_xor(ss, off);
    float rinv = 1.0f / fmaxf(sqrtf(ss), EPS);
    float ox = v.x * rinv, oy = v.y * rinv;
    short hx = f2h(ox), hy = f2h(oy);
    short lx = f2h((ox - h2f(hx)) * LOSCALE);
    short ly = f2h((oy - h2f(hy)) * LOSCALE);
    *(short2*)&csp[(size_t)k * 256 + 2 * lane]       = make_short2(hx, hy);
    *(short2*)&csp[(size_t)k * 256 + 128 + 2 * lane] = make_short2(lx, ly);
    float ss2 = ox * ox + oy * oy;
    #pragma unroll
    for (int off = 32; off; off >>= 1) ss2 += __shfl_xor(ss2, off);
    if (lane == 0) nc[k] = ss2;
}

// Branchless top-2 update (keep first index on ties)
#define UPD(dd, cc, ri) do {                                      \
    bool lt1 = (dd) < d1[ri];                                     \
    float nd2 = lt1 ? d1[ri] : (((dd) < d2[ri]) ? (dd) : d2[ri]); \
    i1[ri] = lt1 ? (cc) : i1[ri];                                 \
    d1[ri] = lt1 ? (dd) : d1[ri];                                 \
    d2[ri] = nd2;                                                 \
} while (0)

__global__ __launch_bounds__(512, 4) void fused_kernel(
    const float* __restrict__ x, const short* __restrict__ csp,
    const float* __restrict__ nc, float* __restrict__ out_norm,
    float* __restrict__ oidx, int* __restrict__ pixinfo,
    _Float16* __restrict__ rows, int do_rows)
{
    __shared__ char smem[SM_BYTES] __attribute__((aligned(16)));
    float* lds_f   = (float*)smem;
    float* nc_s    = (float*)(smem + SM_NC);
    float* mg1     = (float*)(smem + SM_MG1);
    float* mg2     = (float*)(smem + SM_MG2);
    int*   mgi     = (int*)(smem + SM_MGI);
    float* norm_s  = (float*)(smem + SM_NORM);
    float* rinv_s  = (float*)(smem + SM_RINV);
    float* psum    = (float*)(smem + SM_PSUM);

    const int t    = threadIdx.x;
    const int lane = t & 63;
    const int wid  = t >> 6;
    const int wm   = wid >> 1;       // 0..3  (32-pixel row block)
    const int wn   = wid & 1;        // 0..1  (32-centroid half per chunk)
    const int lb15 = lane & 15;
    const int kl4  = lane >> 4;      // 0..3
    const int kl   = kl4 * 16;       // byte offset of k-slice within half-row
    const int lswzB = (lb15 & 7) << 4;   // row&7 XOR-swizzle on byte bits 4-6

    const int pix0 = blockIdx.x * 128;
    const int b    = pix0 >> 12;
    const int px0  = pix0 & (HW - 1);
    const float* xg = x + (size_t)b * (D * HW) + px0;

    // ---- prologue: stage raw x tile [d][px] fp32 ----
    #pragma unroll
    for (int r = 0; r < 16; ++r) {
        int gid = r * 512 + t;
        int d = gid >> 6;
        int px2 = (gid & 63) * 2;
        float2 v = *(const float2*)(xg + (size_t)d * HW + px2);
        *(float2*)&lds_f[d * XSTRIDE + px2] = v;
    }
    nc_s[t] = nc[t];
    __syncthreads();

    // ---- norms ----
    {
        int q = t >> 7, px = t & 127;
        float s = 0.f;
        #pragma unroll
        for (int i = 0; i < 32; ++i) {
            float v = lds_f[(q * 32 + i) * XSTRIDE + px];
            s += v * v;
        }
        psum[q * 128 + px] = s;
    }
    __syncthreads();
    if (t < 128) {
        float s = psum[t] + psum[128 + t] + psum[256 + t] + psum[384 + t];
        float nrm = sqrtf(s);
        norm_s[t] = nrm;
        rinv_s[t] = 1.f / fmaxf(nrm, EPS);
    }
    __syncthreads();

    // ---- write normalized output (fp32, original layout) ----
    float* og = out_norm + (size_t)b * (D * HW) + px0;
    #pragma unroll
    for (int r = 0; r < 16; ++r) {
        int gid = r * 512 + t;
        int d = gid >> 6;
        int px2 = (gid & 63) * 2;
        float2 v = *(float2*)&lds_f[d * XSTRIDE + px2];
        float2 rv = *(float2*)&rinv_s[px2];
        v.x *= rv.x; v.y *= rv.y;
        *(float2*)(og + (size_t)d * HW + px2) = v;
    }

    // ---- build A fragments (fp16 hi + 2048-scaled fp16 lo) in registers ----
    f16x8 ahi[2][4], alo[2][4];
    #pragma unroll
    for (int mf = 0; mf < 2; ++mf) {
        int px = wm * 32 + mf * 16 + lb15;
        float rinv = rinv_s[px];
        #pragma unroll
        for (int kq = 0; kq < 4; ++kq) {
            f16x8 h, l;
            #pragma unroll
            for (int e = 0; e < 8; ++e) {
                int d = kq * 32 + kl4 * 8 + e;
                float v = lds_f[d * XSTRIDE + px] * rinv;
                _Float16 hv = (_Float16)v;
                h[e] = hv;
                l[e] = (_Float16)((v - (float)hv) * LOSCALE);
            }
            ahi[mf][kq] = h; alo[mf][kq] = l;
        }
    }
    __syncthreads();      // x region dead -> becomes B buffers

    // ---- compact pixel-major raw rows (f16), coalesced 64B-line stores ----
    if (do_rows && wn == 0) {
        #pragma unroll
        for (int mf = 0; mf < 2; ++mf) {
            int px = wm * 32 + mf * 16 + lb15;
            float nrm = norm_s[px];
            _Float16* rp = rows + (size_t)(pix0 + px) * 128;
            #pragma unroll
            for (int kq = 0; kq < 4; ++kq) {
                f16x8 rv;
                #pragma unroll
                for (int e = 0; e < 8; ++e) {
                    float raw = ((float)ahi[mf][kq][e] +
                                 (float)alo[mf][kq][e] * RSCALE) * nrm;
                    rv[e] = (_Float16)raw;
                }
                *(f16x8*)(rp + kq * 32 + kl4 * 8) = rv;
            }
        }
    }

    // ---- B staging (global_load_lds, source pre-swizzled g=row&7) ----
    const char* cspb = (const char*)csp;
    auto stageB = [&](int bufoff, int cb) {
        const char* src = cspb + (size_t)cb * 512;
        #pragma unroll
        for (int r = 0; r < 4; ++r) {
            int P  = wid * 4096 + r * 1024;
            int Pl = P + lane * 16;
            int row = Pl >> 9;
            int goff = Pl ^ ((row & 7) << 4);
            __builtin_amdgcn_global_load_lds(
                (const __attribute__((address_space(1))) uint32_t*)(src + goff),
                (__attribute__((address_space(3))) uint32_t*)(smem + bufoff + P),
                16, 0, 0);
        }
    };

    // ---- top-2 state: 8 pixel-rows per lane (mf*4 + j) ----
    float d1[8], d2[8]; int i1[8];
    #pragma unroll
    for (int r = 0; r < 8; ++r) { d1[r] = 3.4e38f; d2[r] = 3.4e38f; i1[r] = 0; }

    stageB(SM_BBUF0, 0);

    for (int c8 = 0; c8 < 8; ++c8) {
        const int cb = c8 * 64;
        const int bufoff = (c8 & 1) ? SM_BBUF1 : SM_BBUF0;
        if (c8 < 7) stageB((c8 & 1) ? SM_BBUF0 : SM_BBUF1, cb + 64);
        if (c8 < 7) { asm volatile("s_waitcnt vmcnt(4)" ::: "memory"); }
        else        { asm volatile("s_waitcnt vmcnt(0)" ::: "memory"); }
        __builtin_amdgcn_s_barrier();
        FENCE();

        f32x4 am[2][2], ac[2][2];   // main + scaled-cross accumulators
        #pragma unroll
        for (int mf = 0; mf < 2; ++mf)
            #pragma unroll
            for (int nf = 0; nf < 2; ++nf) {
                am[mf][nf] = (f32x4){0.f, 0.f, 0.f, 0.f};
                ac[mf][nf] = (f32x4){0.f, 0.f, 0.f, 0.f};
            }

        #pragma unroll
        for (int kq = 0; kq < 4; ++kq) {
            #pragma unroll
            for (int nf = 0; nf < 2; ++nf) {
                const int rowb = (wn * 32 + nf * 16 + lb15) * 512;
                f16x8 bh = *(const f16x8*)(smem + bufoff + rowb + ((kq * 64 + kl) ^ lswzB));
                f16x8 bl = *(const f16x8*)(smem + bufoff + rowb + ((256 + kq * 64 + kl) ^ lswzB));
                #pragma unroll
                for (int mf = 0; mf < 2; ++mf) {
                    am[mf][nf] = __builtin_amdgcn_mfma_f32_16x16x32_f16(ahi[mf][kq], bh, am[mf][nf], 0, 0, 0);
                    ac[mf][nf] = __builtin_amdgcn_mfma_f32_16x16x32_f16(ahi[mf][kq], bl, ac[mf][nf], 0, 0, 0);
                    ac[mf][nf] = __builtin_amdgcn_mfma_f32_16x16x32_f16(alo[mf][kq], bh, ac[mf][nf], 0, 0, 0);
                }
            }
        }

        // online top-2 from this chunk: dist = nc - 2*main - (2/2048)*cross
        #pragma unroll
        for (int nf = 0; nf < 2; ++nf) {
            int cid = cb + wn * 32 + nf * 16 + lb15;
            float ncv = nc_s[cid];
            #pragma unroll
            for (int mf = 0; mf < 2; ++mf) {
                #pragma unroll
                for (int j = 0; j < 4; ++j) {
                    int ri = mf * 4 + j;
                    float dd = ncv - 2.f * am[mf][nf][j] - (2.f * RSCALE) * ac[mf][nf][j];
                    UPD(dd, cid, ri);
                }
            }
        }

        FENCE();
        __builtin_amdgcn_s_barrier();
        FENCE();
    }

    // ---- butterfly merge across the 16 centroid lanes ----
    #pragma unroll
    for (int r = 0; r < 8; ++r) {
        #pragma unroll
        for (int m = 1; m < 16; m <<= 1) {
            float o1 = __shfl_xor(d1[r], m);
            float o2 = __shfl_xor(d2[r], m);
            int   oi = __shfl_xor(i1[r], m);
            bool take = (o1 < d1[r]) || (o1 == d1[r] && oi < i1[r]);
            float loser = take ? d1[r] : o1;
            d2[r] = fminf(loser, fminf(d2[r], o2));
            if (take) { d1[r] = o1; i1[r] = oi; }
        }
    }
    if (lb15 == 0) {
        #pragma unroll
        for (int mf = 0; mf < 2; ++mf)
            #pragma unroll
            for (int j = 0; j < 4; ++j) {
                int row = wm * 32 + mf * 16 + kl4 * 4 + j;
                mg1[wn * 128 + row] = d1[mf * 4 + j];
                mg2[wn * 128 + row] = d2[mf * 4 + j];
                mgi[wn * 128 + row] = i1[mf * 4 + j];
            }
    }
    __syncthreads();

    // ---- final cross-wave merge, idx/mask outputs ----
    if (t < 128) {
        float bd1 = 3.4e38f, bd2 = 3.4e38f; int bi = 0;
        #pragma unroll
        for (int w = 0; w < 2; ++w) {
            float a1 = mg1[w * 128 + t], a2 = mg2[w * 128 + t];
            int ai = mgi[w * 128 + t];
            if (a1 < bd1 || (a1 == bd1 && ai < bi)) {
                bd2 = fminf(bd1, fminf(a2, bd2));
                bd1 = a1; bi = ai;
            } else {
                bd2 = fminf(bd2, a1);
            }
        }
        oidx[pix0 + t] = (float)bi;
        bool sel = (bd2 - bd1) > MARGIN;
        pixinfo[pix0 + t] = sel ? bi : -1;
    }
}

// Segment sum without per-element atomics: 4 blocks per cluster, each scans a
// quarter of pixinfo (L2-resident) and sums matching rows; one 128-float
// atomicAdd per block.
__global__ __launch_bounds__(256) void segsum_kernel(
    const float* __restrict__ x, const _Float16* __restrict__ rows,
    const int* __restrict__ pixinfo, float* __restrict__ csum,
    float* __restrict__ ccnt, int use_rows)
{
    __shared__ float psum[4 * 128];
    __shared__ int pcnt[4];
    const int kc   = blockIdx.x >> 2;
    const int qtr  = blockIdx.x & 3;
    const int lane = threadIdx.x & 63;
    const int w    = threadIdx.x >> 6;
    const int base = qtr * 65536 + w * 16384;

    float a0 = 0.f, a1 = 0.f;
    int cnt = 0;
    for (int it = 0; it < 256; ++it) {
        int ibase = base + it * 64;
        int v = pixinfo[ibase + lane];
        unsigned long long m = __ballot(v == kc);
        cnt += (int)__popcll(m);
        while (m) {
            int bpos = __builtin_ctzll(m);
            m &= m - 1;
            int pid = ibase + bpos;
            if (use_rows) {
                const _Float16* rp = rows + (size_t)pid * 128;
                f16x2 hv = *(const f16x2*)(rp + 2 * lane);
                a0 += (float)hv[0];
                a1 += (float)hv[1];
            } else {
                const float* xp = x + ((size_t)(pid >> 12)) * (D * HW) + (pid & (HW - 1));
                a0 += xp[(size_t)(2 * lane) * HW];
                a1 += xp[(size_t)(2 * lane + 1) * HW];
            }
        }
    }
    psum[w * 128 + 2 * lane]     = a0;
    psum[w * 128 + 2 * lane + 1] = a1;
    if (lane == 0) pcnt[w] = cnt;
    __syncthreads();
    if (threadIdx.x < 128) {
        float s = psum[threadIdx.x] + psum[128 + threadIdx.x] +
                  psum[256 + threadIdx.x] + psum[384 + threadIdx.x];
        atomicAdd(&csum[(size_t)kc * D + threadIdx.x], s);
    }
    if (threadIdx.x == 0) {
        float c = (float)(pcnt[0] + pcnt[1] + pcnt[2] + pcnt[3]);
        atomicAdd(&ccnt[kc], c);
    }
}

extern "C" void kernel_launch(void* const* d_in, const int* in_sizes, int n_in,
                              void* d_out, int out_size, void* d_ws, size_t ws_size,
                              hipStream_t stream) {
    const float* x   = (const float*)d_in[0];
    const float* cen = (const float*)d_in[1];

    float* out      = (float*)d_out;
    float* out_norm = out;                       // 33554432
    float* csum     = out + OUT_NORM_ELEMS;      // 512*128
    float* ccnt     = csum + (size_t)K * D;      // 512
    float* oidx     = ccnt + K;                  // 262144

    char* ws = (char*)d_ws;
    short*     csp     = (short*)ws;                           // 262144 B
    float*     nc      = (float*)(ws + 262144);                // 2 KB
    int*       pixinfo = (int*)(ws + 264192);                  // 1 MB
    _Float16*  rows    = (_Float16*)(ws + 1312768);            // 67,108,864 B
    const size_t need  = 1312768ull + (size_t)NPIX * D * 2;
    int use_rows = (ws_size >= need) ? 1 : 0;

    hipLaunchKernelGGL(zero_kernel, dim3((K * D + K + 255) / 256), dim3(256), 0, stream,
                       csum, K * D + K);
    hipLaunchKernelGGL(normalize_centroids, dim3(K / 4), dim3(256), 0, stream,
                       cen, csp, nc);
    hipLaunchKernelGGL(fused_kernel, dim3(NPIX / 128), dim3(512), 0, stream,
                       x, csp, nc, out_norm, oidx, pixinfo, rows, use_rows);
    hipLaunchKernelGGL(segsum_kernel, dim3(K * 4), dim3(256), 0, stream,
                       x, rows, pixinfo, csum, ccnt, use_rows);
}